// Round 2
// baseline (232.776 us; speedup 1.0000x reference)
//
#include <hip/hip_runtime.h>

typedef __attribute__((ext_vector_type(8))) short bf16x8;
typedef __attribute__((ext_vector_type(4))) short bf16x4;
typedef __attribute__((ext_vector_type(4))) float f32x4;
typedef __attribute__((ext_vector_type(4))) float floatx4;

__device__ __forceinline__ unsigned short f2bf(float f) {
    unsigned int u = __float_as_uint(f);
    u += 0x7fffu + ((u >> 16) & 1u);   // round-to-nearest-even
    return (unsigned short)(u >> 16);
}
__device__ __forceinline__ float bf2f_s(short h) {
    return __uint_as_float(((unsigned int)(unsigned short)h) << 16);
}

// ---------------- kernel 0: weight conversion to bf16 ----------------
// Wkvb[256][1024]: rows 0-127 = Wk, rows 128-255 = Wv.  Wob[1024][128] = Wo.
__global__ void k_convert(const float* __restrict__ Wk, const float* __restrict__ Wv,
                          const float* __restrict__ Wo,
                          unsigned short* __restrict__ Wkvb, unsigned short* __restrict__ Wob) {
    int i = (blockIdx.x * blockDim.x + threadIdx.x) * 4;
    if (i < 131072) {
        floatx4 a = *reinterpret_cast<const floatx4*>(Wk + i);
        floatx4 b = *reinterpret_cast<const floatx4*>(Wv + i);
        floatx4 c = *reinterpret_cast<const floatx4*>(Wo + i);
        bf16x4 sa, sb, sc;
        #pragma unroll
        for (int e = 0; e < 4; ++e) {
            sa[e] = (short)f2bf(a[e]); sb[e] = (short)f2bf(b[e]); sc[e] = (short)f2bf(c[e]);
        }
        *reinterpret_cast<bf16x4*>(Wkvb + i)          = sa;
        *reinterpret_cast<bf16x4*>(Wkvb + 131072 + i) = sb;
        *reinterpret_cast<bf16x4*>(Wob + i)           = sc;
    }
}

// ---------------- kernel 1: keys/vals GEMM ----------------
// kv[m][n] = sum_e patches[m][e] * Wkvb[n][e]  (+ patch_pos bias for n<128)
// Tile 64(M) x 256(N=all), BK=64. 8 waves, wave tile 32M x 64N.
// A: f32->bf16 reg-staged into LDS, double-buffered, ONE barrier per K-step.
// B: fragments loaded directly from global (L2-resident), prefetched in regs.
__global__ __launch_bounds__(512, 4)
void k_keysvals(const float* __restrict__ patches,
                const unsigned short* __restrict__ Wkvb,
                const float* __restrict__ patch_pos,
                unsigned short* __restrict__ kv)
{
    __shared__ unsigned short As[2][64][80];   // stride 80: 16B-aligned b128, conflict-free

    const int tid  = threadIdx.x;
    const int lane = tid & 63;
    const int wave = tid >> 6;      // 0..7
    const int wm   = wave >> 2;     // 0..1  (32-row half)
    const int wn   = wave & 3;      // 0..3  (64-col quarter)
    const int l15  = lane & 15;
    const int lg   = lane >> 4;     // 0..3
    const int row0 = blockIdx.x * 64;

    // A staging: thread -> (row ar, col ac), 8 floats
    const int ar = tid >> 3;            // 0..63
    const int ac = (tid & 7) * 8;       // 0..56
    const float* aptr = patches + (size_t)(row0 + ar) * 1024 + ac;

    // B fragment base: row n = wn*64 + ni*16 + l15, k-chunk lg*8
    const unsigned short* bptr = Wkvb + (size_t)(wn * 64 + l15) * 1024 + lg * 8;

    f32x4 acc[2][4];
    #pragma unroll
    for (int i = 0; i < 2; ++i)
        #pragma unroll
        for (int j = 0; j < 4; ++j)
            acc[i][j] = (f32x4){0.f, 0.f, 0.f, 0.f};

    floatx4 a0, a1;
    bf16x8 breg[2][4];

    // ---- prologue: tile 0 ----
    a0 = *reinterpret_cast<const floatx4*>(aptr);
    a1 = *reinterpret_cast<const floatx4*>(aptr + 4);
    #pragma unroll
    for (int kk = 0; kk < 2; ++kk)
        #pragma unroll
        for (int ni = 0; ni < 4; ++ni)
            breg[kk][ni] = *reinterpret_cast<const bf16x8*>(bptr + (size_t)ni * 16 * 1024 + kk * 32);
    {
        bf16x8 sv;
        #pragma unroll
        for (int e = 0; e < 4; ++e) { sv[e] = (short)f2bf(a0[e]); sv[4 + e] = (short)f2bf(a1[e]); }
        *reinterpret_cast<bf16x8*>(&As[0][ar][ac]) = sv;
    }
    __syncthreads();

    int cur = 0;
    for (int t = 0; t < 16; ++t) {
        const int konext = (t + 1) * 64;
        // prefetch A(t+1) -> regs (in flight during compute)
        if (t < 15) {
            a0 = *reinterpret_cast<const floatx4*>(aptr + konext);
            a1 = *reinterpret_cast<const floatx4*>(aptr + konext + 4);
        }
        __builtin_amdgcn_sched_barrier(0);  // pin prefetch issue above compute

        // compute on As[cur] with breg(t)
        #pragma unroll
        for (int kk = 0; kk < 2; ++kk) {
            bf16x8 af[2];
            #pragma unroll
            for (int mi = 0; mi < 2; ++mi)
                af[mi] = *reinterpret_cast<const bf16x8*>(&As[cur][wm * 32 + mi * 16 + l15][kk * 32 + lg * 8]);
            #pragma unroll
            for (int mi = 0; mi < 2; ++mi)
                #pragma unroll
                for (int ni = 0; ni < 4; ++ni)
                    acc[mi][ni] = __builtin_amdgcn_mfma_f32_16x16x32_bf16(af[mi], breg[kk][ni], acc[mi][ni], 0, 0, 0);
        }

        if (t < 15) {
            // prefetch B(t+1) (regs free after MFMA issue)
            #pragma unroll
            for (int kk = 0; kk < 2; ++kk)
                #pragma unroll
                for (int ni = 0; ni < 4; ++ni)
                    breg[kk][ni] = *reinterpret_cast<const bf16x8*>(bptr + (size_t)ni * 16 * 1024 + konext + kk * 32);
            // convert A(t+1) and write other buffer; single barrier per K-step
            bf16x8 sv;
            #pragma unroll
            for (int e = 0; e < 4; ++e) { sv[e] = (short)f2bf(a0[e]); sv[4 + e] = (short)f2bf(a1[e]); }
            *reinterpret_cast<bf16x8*>(&As[cur ^ 1][ar][ac]) = sv;
            __syncthreads();
            cur ^= 1;
        }
    }

    // epilogue: C/D layout col=lane&15 (n), row=(lane>>4)*4+i (m)
    #pragma unroll
    for (int mi = 0; mi < 2; ++mi) {
        #pragma unroll
        for (int i = 0; i < 4; ++i) {
            int m  = row0 + wm * 32 + mi * 16 + lg * 4 + i;
            int kp = m % 196;
            #pragma unroll
            for (int ni = 0; ni < 4; ++ni) {
                int n = wn * 64 + ni * 16 + l15;
                float v = acc[mi][ni][i];
                if (n < 128) v += patch_pos[kp * 128 + n];
                kv[(size_t)m * 256 + n] = f2bf(v);
            }
        }
    }
}

// ---------------- kernel 2: per-batch attention ----------------
__global__ __launch_bounds__(1024)
void k_attn(const unsigned short* __restrict__ kv,
            const float* __restrict__ queries,
            const float* __restrict__ prior,
            const float* __restrict__ temperature,
            float* __restrict__ attn_out,
            unsigned short* __restrict__ att)
{
    __shared__ unsigned short k_s[196][136];
    __shared__ unsigned short v_s[196][128];
    __shared__ unsigned short q_s[52][128];
    __shared__ float          l_s[52][196];

    const int b   = blockIdx.x;
    const int tid = threadIdx.x;
    const size_t base = (size_t)b * 196 * 256;

    for (int idx = tid; idx < 6272; idx += 1024) {
        int row = idx >> 5;
        int c   = (idx & 31) * 8;
        bf16x8 v = *reinterpret_cast<const bf16x8*>(kv + base + row * 256 + c);
        if (c < 128) *reinterpret_cast<bf16x8*>(&k_s[row][c])       = v;
        else         *reinterpret_cast<bf16x8*>(&v_s[row][c - 128]) = v;
    }
    for (int idx = tid; idx < 1664; idx += 1024) {
        int row = idx >> 5;
        int c   = (idx & 31) * 4;
        const float* qp = queries + row * 128 + c;
        bf16x4 sv;
        sv[0] = (short)f2bf(qp[0]); sv[1] = (short)f2bf(qp[1]);
        sv[2] = (short)f2bf(qp[2]); sv[3] = (short)f2bf(qp[3]);
        *reinterpret_cast<bf16x4*>(&q_s[row][c]) = sv;
    }
    __syncthreads();

    const float inv_temp  = 1.0f / (log1pf(expf(temperature[0])) + 0.5f);
    const float inv_scale = 0.08838834764831845f;

    for (int task = tid; task < 3328; task += 1024) {
        int q  = task >> 6;
        int kg = task & 63;
        if (kg < 49) {
            float dot0 = 0.f, dot1 = 0.f, dot2 = 0.f, dot3 = 0.f;
            #pragma unroll 4
            for (int c = 0; c < 128; c += 8) {
                bf16x8 qv = *reinterpret_cast<const bf16x8*>(&q_s[q][c]);
                float qf[8];
                #pragma unroll
                for (int e = 0; e < 8; ++e) qf[e] = bf2f_s(qv[e]);
                bf16x8 k0v = *reinterpret_cast<const bf16x8*>(&k_s[kg][c]);
                bf16x8 k1v = *reinterpret_cast<const bf16x8*>(&k_s[kg + 49][c]);
                bf16x8 k2v = *reinterpret_cast<const bf16x8*>(&k_s[kg + 98][c]);
                bf16x8 k3v = *reinterpret_cast<const bf16x8*>(&k_s[kg + 147][c]);
                #pragma unroll
                for (int e = 0; e < 8; ++e) {
                    dot0 += qf[e] * bf2f_s(k0v[e]);
                    dot1 += qf[e] * bf2f_s(k1v[e]);
                    dot2 += qf[e] * bf2f_s(k2v[e]);
                    dot3 += qf[e] * bf2f_s(k3v[e]);
                }
            }
            int k;
            k = kg;       l_s[q][k] = (dot0 * inv_scale + prior[q * 196 + k]) * inv_temp;
            k = kg + 49;  l_s[q][k] = (dot1 * inv_scale + prior[q * 196 + k]) * inv_temp;
            k = kg + 98;  l_s[q][k] = (dot2 * inv_scale + prior[q * 196 + k]) * inv_temp;
            k = kg + 147; l_s[q][k] = (dot3 * inv_scale + prior[q * 196 + k]) * inv_temp;
        }
    }
    __syncthreads();

    const int lane = tid & 63;
    const int wave = tid >> 6;
    for (int q = wave; q < 52; q += 16) {
        float x0 = l_s[q][lane];
        float x1 = l_s[q][lane + 64];
        float x2 = l_s[q][lane + 128];
        float x3 = (lane < 4) ? l_s[q][lane + 192] : -1e30f;
        float m = fmaxf(fmaxf(x0, x1), fmaxf(x2, x3));
        #pragma unroll
        for (int off = 32; off > 0; off >>= 1) m = fmaxf(m, __shfl_xor(m, off));
        float e0 = expf(x0 - m), e1 = expf(x1 - m), e2 = expf(x2 - m);
        float e3 = (lane < 4) ? expf(x3 - m) : 0.0f;
        float s = e0 + e1 + e2 + e3;
        #pragma unroll
        for (int off = 32; off > 0; off >>= 1) s += __shfl_xor(s, off);
        float inv = 1.0f / s;
        float* po = attn_out + ((size_t)b * 52 + q) * 196;
        float a0 = e0 * inv, a1 = e1 * inv, a2 = e2 * inv;
        l_s[q][lane]       = a0;  po[lane]       = a0;
        l_s[q][lane + 64]  = a1;  po[lane + 64]  = a1;
        l_s[q][lane + 128] = a2;  po[lane + 128] = a2;
        if (lane < 4) { float a3 = e3 * inv; l_s[q][lane + 192] = a3; po[lane + 192] = a3; }
    }
    __syncthreads();

    if (tid < 832) {
        int q  = tid >> 4;
        int a0 = (tid & 15) * 8;
        float accv[8] = {0.f, 0.f, 0.f, 0.f, 0.f, 0.f, 0.f, 0.f};
        for (int k = 0; k < 196; ++k) {
            float w = l_s[q][k];
            bf16x8 vv = *reinterpret_cast<const bf16x8*>(&v_s[k][a0]);
            #pragma unroll
            for (int e = 0; e < 8; ++e) accv[e] += w * bf2f_s(vv[e]);
        }
        bf16x8 sv;
        #pragma unroll
        for (int e = 0; e < 8; ++e) sv[e] = (short)f2bf(accv[e]);
        *reinterpret_cast<bf16x8*>(att + ((size_t)b * 52 + q) * 128 + a0) = sv;
    }
}

// ---------------- kernel 3: output GEMM (LDS-free, one wave per 32x64 tile) ----------------
// out[m][e] = sum_a att[m][a] * Wob[e][a] + bo[e],  m in [0,13312), e in [0,1024)
__global__ __launch_bounds__(256)
void k_out(const unsigned short* __restrict__ att,
           const unsigned short* __restrict__ Wob,
           const float* __restrict__ bo,
           float* __restrict__ out)
{
    const int w    = (blockIdx.x * 256 + threadIdx.x) >> 6;   // global wave id
    const int lane = threadIdx.x & 63;
    const int l15  = lane & 15;
    const int lg   = lane >> 4;
    const int mt   = w % 416;          // 13312/32
    const int et   = w / 416;          // 1024/64
    const int m0   = mt * 32;
    const int e0   = et * 64;

    f32x4 acc[2][4];
    #pragma unroll
    for (int i = 0; i < 2; ++i)
        #pragma unroll
        for (int j = 0; j < 4; ++j)
            acc[i][j] = (f32x4){0.f, 0.f, 0.f, 0.f};

    const unsigned short* ap = att + (size_t)(m0 + l15) * 128 + lg * 8;
    const unsigned short* bp = Wob + (size_t)(e0 + l15) * 128 + lg * 8;

    #pragma unroll
    for (int kk = 0; kk < 4; ++kk) {
        bf16x8 af[2], bfr[4];
        af[0] = *reinterpret_cast<const bf16x8*>(ap + kk * 32);
        af[1] = *reinterpret_cast<const bf16x8*>(ap + 16 * 128 + kk * 32);
        #pragma unroll
        for (int ni = 0; ni < 4; ++ni)
            bfr[ni] = *reinterpret_cast<const bf16x8*>(bp + (size_t)ni * 16 * 128 + kk * 32);
        #pragma unroll
        for (int mi = 0; mi < 2; ++mi)
            #pragma unroll
            for (int ni = 0; ni < 4; ++ni)
                acc[mi][ni] = __builtin_amdgcn_mfma_f32_16x16x32_bf16(af[mi], bfr[ni], acc[mi][ni], 0, 0, 0);
    }

    float bov[4];
    #pragma unroll
    for (int ni = 0; ni < 4; ++ni) bov[ni] = bo[e0 + ni * 16 + l15];

    #pragma unroll
    for (int mi = 0; mi < 2; ++mi) {
        #pragma unroll
        for (int i = 0; i < 4; ++i) {
            int m = m0 + mi * 16 + lg * 4 + i;
            #pragma unroll
            for (int ni = 0; ni < 4; ++ni)
                out[(size_t)m * 1024 + e0 + ni * 16 + l15] = acc[mi][ni][i] + bov[ni];
        }
    }
}

extern "C" void kernel_launch(void* const* d_in, const int* in_sizes, int n_in,
                              void* d_out, int out_size, void* d_ws, size_t ws_size,
                              hipStream_t stream)
{
    const float* patches     = (const float*)d_in[0];   // [256][196][1024]
    const float* queries     = (const float*)d_in[1];   // [52][128]
    const float* Wk          = (const float*)d_in[2];   // [128][1024]
    const float* Wv          = (const float*)d_in[3];   // [128][1024]
    const float* Wo          = (const float*)d_in[4];   // [1024][128]
    const float* bo          = (const float*)d_in[5];   // [1024]
    const float* patch_pos   = (const float*)d_in[6];   // [196][128]
    const float* temperature = (const float*)d_in[7];   // [1]
    const float* prior       = (const float*)d_in[8];   // [52][196]

    float* out      = (float*)d_out;                    // [256*52][1024]
    float* attn_out = out + (size_t)256 * 52 * 1024;    // [256*52][196]

    unsigned short* Wkvb = (unsigned short*)d_ws;              // 256*1024
    unsigned short* Wob  = Wkvb + 256 * 1024;                  // 1024*128
    unsigned short* kv   = Wob + 1024 * 128;                   // 50176*256
    unsigned short* att  = kv + (size_t)50176 * 256;           // 13312*128

    k_convert <<<128, 256, 0, stream>>>(Wk, Wv, Wo, Wkvb, Wob);
    k_keysvals<<<784, 512, 0, stream>>>(patches, Wkvb, patch_pos, kv);
    k_attn    <<<256, 1024, 0, stream>>>(kv, queries, prior, temperature, attn_out, att);
    k_out     <<<dim3(1664), 256, 0, stream>>>(att, Wob, bo, out);
}

// Round 3
// 158.935 us; speedup vs baseline: 1.4646x; 1.4646x over previous
//
#include <hip/hip_runtime.h>

typedef __attribute__((ext_vector_type(8))) short bf16x8;
typedef __attribute__((ext_vector_type(4))) short bf16x4;
typedef __attribute__((ext_vector_type(4))) float f32x4;
typedef __attribute__((ext_vector_type(4))) float floatx4;

__device__ __forceinline__ unsigned short f2bf(float f) {
    unsigned int u = __float_as_uint(f);
    u += 0x7fffu + ((u >> 16) & 1u);   // round-to-nearest-even
    return (unsigned short)(u >> 16);
}
__device__ __forceinline__ float bf2f_s(short h) {
    return __uint_as_float(((unsigned int)(unsigned short)h) << 16);
}

// async global->LDS, 16B per lane. LDS dest must be linear (wave-uniform base + lane*16).
__device__ __forceinline__ void gload_lds16(const void* gsrc, void* ldst) {
    __builtin_amdgcn_global_load_lds(
        (const __attribute__((address_space(1))) unsigned int*)gsrc,
        (__attribute__((address_space(3))) unsigned int*)ldst, 16, 0, 0);
}

// pack 8 f32 -> bf16x8 via HW packed convert (RNE)
__device__ __forceinline__ bf16x8 cvt8(f32x4 lo, f32x4 hi) {
    union { unsigned int u[4]; bf16x8 v; } r;
    asm("v_cvt_pk_bf16_f32 %0, %1, %2" : "=v"(r.u[0]) : "v"(lo[0]), "v"(lo[1]));
    asm("v_cvt_pk_bf16_f32 %0, %1, %2" : "=v"(r.u[1]) : "v"(lo[2]), "v"(lo[3]));
    asm("v_cvt_pk_bf16_f32 %0, %1, %2" : "=v"(r.u[2]) : "v"(hi[0]), "v"(hi[1]));
    asm("v_cvt_pk_bf16_f32 %0, %1, %2" : "=v"(r.u[3]) : "v"(hi[2]), "v"(hi[3]));
    return r.v;
}

// ---------------- kernel 0: weight conversion to bf16 ----------------
__global__ void k_convert(const float* __restrict__ Wk, const float* __restrict__ Wv,
                          const float* __restrict__ Wo,
                          unsigned short* __restrict__ Wkvb, unsigned short* __restrict__ Wob) {
    int i = (blockIdx.x * blockDim.x + threadIdx.x) * 4;
    if (i < 131072) {
        floatx4 a = *reinterpret_cast<const floatx4*>(Wk + i);
        floatx4 b = *reinterpret_cast<const floatx4*>(Wv + i);
        floatx4 c = *reinterpret_cast<const floatx4*>(Wo + i);
        bf16x4 sa, sb, sc;
        #pragma unroll
        for (int e = 0; e < 4; ++e) {
            sa[e] = (short)f2bf(a[e]); sb[e] = (short)f2bf(b[e]); sc[e] = (short)f2bf(c[e]);
        }
        *reinterpret_cast<bf16x4*>(Wkvb + i)          = sa;
        *reinterpret_cast<bf16x4*>(Wkvb + 131072 + i) = sb;
        *reinterpret_cast<bf16x4*>(Wob + i)           = sc;
    }
}

// ---------------- kernel 1: keys/vals GEMM (m97-style) ----------------
// kv[m][n] = sum_e patches[m][e] * Wkvb[n][e]  (+ patch_pos bias for n<128)
// Block tile 64M x 128N, BK=64, 256 threads (4 waves, wave tile 32M x 64N).
// A (f32) + B (bf16) staged via global_load_lds with pre-swizzled global source;
// ds_read side applies the same XOR swizzle. Single LDS buffer, 2 barriers/K-step.
__global__ __launch_bounds__(256, 4)
void k_keysvals(const float* __restrict__ patches,
                const unsigned short* __restrict__ Wkvb,
                const float* __restrict__ patch_pos,
                unsigned short* __restrict__ kv)
{
    __shared__ float          As[64 * 64];            // [64 rows][16 granules of 16B], swizzled g^(r&15)
    __shared__ unsigned short Bs[128 * 64];           // [128 rows][8 granules of 16B], swizzled g^(r&7)

    const int tid  = threadIdx.x;
    const int lane = tid & 63;
    const int wave = tid >> 6;      // 0..3
    const int wm   = wave >> 1;     // 0..1 : 32-row half
    const int wn   = wave & 1;      // 0..1 : 64-col half
    const int l15  = lane & 15;
    const int lg   = lane >> 4;     // 0..3

    const int bid  = blockIdx.x;
    const int nb   = bid & 1;            // N half
    const int mt   = bid >> 1;           // M tile
    const int row0 = mt * 64;
    const int n0   = nb * 128;

    // staging source bases (pre-swizzled granule index, constant across K-steps)
    const int arow = tid >> 4;                         // 0..15 (+ i*16)
    const int agn  = (tid & 15) ^ arow;                // A granule ^ row&15
    const char* agbase = (const char*)(patches + (size_t)(row0 + arow) * 1024) + agn * 16;

    const int brow = tid >> 3;                         // 0..31 (+ i*32)
    const int bgn  = (tid & 7) ^ (brow & 7);           // B granule ^ row&7
    const char* bgbase = (const char*)(Wkvb + (size_t)(n0 + brow) * 1024) + bgn * 16;

    char* alds = (char*)As + tid * 16;                 // + i*4096
    char* blds = (char*)Bs + tid * 16;

    f32x4 acc[2][4];
    #pragma unroll
    for (int i = 0; i < 2; ++i)
        #pragma unroll
        for (int j = 0; j < 4; ++j)
            acc[i][j] = (f32x4){0.f, 0.f, 0.f, 0.f};

    for (int t = 0; t < 16; ++t) {
        const int koA = t * 256;   // byte offset: t*64 floats
        const int koB = t * 128;   // byte offset: t*64 bf16
        #pragma unroll
        for (int i = 0; i < 4; ++i)
            gload_lds16(agbase + (size_t)i * 65536 + koA, alds + i * 4096);
        #pragma unroll
        for (int i = 0; i < 4; ++i)
            gload_lds16(bgbase + (size_t)i * 65536 + koB, blds + i * 4096);
        __syncthreads();   // drains vmcnt -> tile resident

        #pragma unroll
        for (int kk = 0; kk < 2; ++kk) {
            bf16x8 af[2];
            #pragma unroll
            for (int mi = 0; mi < 2; ++mi) {
                const int mrow = wm * 32 + mi * 16 + l15;
                const int q0   = (kk * 8 + lg * 2) ^ l15;      // granule of k lg*8+0..3
                const int q1   = q0 ^ 1;                       // granule of k lg*8+4..7
                f32x4 lo = *reinterpret_cast<const f32x4*>((const char*)As + mrow * 256 + q0 * 16);
                f32x4 hi = *reinterpret_cast<const f32x4*>((const char*)As + mrow * 256 + q1 * 16);
                af[mi] = cvt8(lo, hi);
            }
            #pragma unroll
            for (int ni = 0; ni < 4; ++ni) {
                const int nrow = wn * 64 + ni * 16 + l15;
                const int qb   = (kk * 4 + lg) ^ (l15 & 7);
                bf16x8 bf = *reinterpret_cast<const bf16x8*>((const char*)Bs + nrow * 128 + qb * 16);
                #pragma unroll
                for (int mi = 0; mi < 2; ++mi)
                    acc[mi][ni] = __builtin_amdgcn_mfma_f32_16x16x32_bf16(af[mi], bf, acc[mi][ni], 0, 0, 0);
            }
        }
        __syncthreads();   // all reads done before next overwrite
    }

    // epilogue: C/D layout col=lane&15 (n), row=(lane>>4)*4+i (m)
    #pragma unroll
    for (int mi = 0; mi < 2; ++mi) {
        #pragma unroll
        for (int i = 0; i < 4; ++i) {
            int m  = row0 + wm * 32 + mi * 16 + lg * 4 + i;
            int kp = m % 196;
            #pragma unroll
            for (int ni = 0; ni < 4; ++ni) {
                int n = n0 + wn * 64 + ni * 16 + l15;
                float v = acc[mi][ni][i];
                if (n < 128) v += patch_pos[kp * 128 + n];
                kv[(size_t)m * 256 + n] = f2bf(v);
            }
        }
    }
}

// ---------------- kernel 2: per-batch attention ----------------
__global__ __launch_bounds__(1024)
void k_attn(const unsigned short* __restrict__ kv,
            const float* __restrict__ queries,
            const float* __restrict__ prior,
            const float* __restrict__ temperature,
            float* __restrict__ attn_out,
            unsigned short* __restrict__ att)
{
    __shared__ unsigned short k_s[196][136];
    __shared__ unsigned short v_s[196][128];
    __shared__ unsigned short q_s[52][128];
    __shared__ float          l_s[52][196];

    const int b   = blockIdx.x;
    const int tid = threadIdx.x;
    const size_t base = (size_t)b * 196 * 256;

    for (int idx = tid; idx < 6272; idx += 1024) {
        int row = idx >> 5;
        int c   = (idx & 31) * 8;
        bf16x8 v = *reinterpret_cast<const bf16x8*>(kv + base + row * 256 + c);
        if (c < 128) *reinterpret_cast<bf16x8*>(&k_s[row][c])       = v;
        else         *reinterpret_cast<bf16x8*>(&v_s[row][c - 128]) = v;
    }
    for (int idx = tid; idx < 1664; idx += 1024) {
        int row = idx >> 5;
        int c   = (idx & 31) * 4;
        const float* qp = queries + row * 128 + c;
        bf16x4 sv;
        sv[0] = (short)f2bf(qp[0]); sv[1] = (short)f2bf(qp[1]);
        sv[2] = (short)f2bf(qp[2]); sv[3] = (short)f2bf(qp[3]);
        *reinterpret_cast<bf16x4*>(&q_s[row][c]) = sv;
    }
    __syncthreads();

    const float inv_temp  = 1.0f / (log1pf(expf(temperature[0])) + 0.5f);
    const float inv_scale = 0.08838834764831845f;

    for (int task = tid; task < 3328; task += 1024) {
        int q  = task >> 6;
        int kg = task & 63;
        if (kg < 49) {
            float dot0 = 0.f, dot1 = 0.f, dot2 = 0.f, dot3 = 0.f;
            #pragma unroll 4
            for (int c = 0; c < 128; c += 8) {
                bf16x8 qv = *reinterpret_cast<const bf16x8*>(&q_s[q][c]);
                float qf[8];
                #pragma unroll
                for (int e = 0; e < 8; ++e) qf[e] = bf2f_s(qv[e]);
                bf16x8 k0v = *reinterpret_cast<const bf16x8*>(&k_s[kg][c]);
                bf16x8 k1v = *reinterpret_cast<const bf16x8*>(&k_s[kg + 49][c]);
                bf16x8 k2v = *reinterpret_cast<const bf16x8*>(&k_s[kg + 98][c]);
                bf16x8 k3v = *reinterpret_cast<const bf16x8*>(&k_s[kg + 147][c]);
                #pragma unroll
                for (int e = 0; e < 8; ++e) {
                    dot0 += qf[e] * bf2f_s(k0v[e]);
                    dot1 += qf[e] * bf2f_s(k1v[e]);
                    dot2 += qf[e] * bf2f_s(k2v[e]);
                    dot3 += qf[e] * bf2f_s(k3v[e]);
                }
            }
            int k;
            k = kg;       l_s[q][k] = (dot0 * inv_scale + prior[q * 196 + k]) * inv_temp;
            k = kg + 49;  l_s[q][k] = (dot1 * inv_scale + prior[q * 196 + k]) * inv_temp;
            k = kg + 98;  l_s[q][k] = (dot2 * inv_scale + prior[q * 196 + k]) * inv_temp;
            k = kg + 147; l_s[q][k] = (dot3 * inv_scale + prior[q * 196 + k]) * inv_temp;
        }
    }
    __syncthreads();

    const int lane = tid & 63;
    const int wave = tid >> 6;
    for (int q = wave; q < 52; q += 16) {
        float x0 = l_s[q][lane];
        float x1 = l_s[q][lane + 64];
        float x2 = l_s[q][lane + 128];
        float x3 = (lane < 4) ? l_s[q][lane + 192] : -1e30f;
        float m = fmaxf(fmaxf(x0, x1), fmaxf(x2, x3));
        #pragma unroll
        for (int off = 32; off > 0; off >>= 1) m = fmaxf(m, __shfl_xor(m, off));
        float e0 = expf(x0 - m), e1 = expf(x1 - m), e2 = expf(x2 - m);
        float e3 = (lane < 4) ? expf(x3 - m) : 0.0f;
        float s = e0 + e1 + e2 + e3;
        #pragma unroll
        for (int off = 32; off > 0; off >>= 1) s += __shfl_xor(s, off);
        float inv = 1.0f / s;
        float* po = attn_out + ((size_t)b * 52 + q) * 196;
        float a0 = e0 * inv, a1 = e1 * inv, a2 = e2 * inv;
        l_s[q][lane]       = a0;  po[lane]       = a0;
        l_s[q][lane + 64]  = a1;  po[lane + 64]  = a1;
        l_s[q][lane + 128] = a2;  po[lane + 128] = a2;
        if (lane < 4) { float a3 = e3 * inv; l_s[q][lane + 192] = a3; po[lane + 192] = a3; }
    }
    __syncthreads();

    if (tid < 832) {
        int q  = tid >> 4;
        int a0 = (tid & 15) * 8;
        float accv[8] = {0.f, 0.f, 0.f, 0.f, 0.f, 0.f, 0.f, 0.f};
        for (int k = 0; k < 196; ++k) {
            float w = l_s[q][k];
            bf16x8 vv = *reinterpret_cast<const bf16x8*>(&v_s[k][a0]);
            #pragma unroll
            for (int e = 0; e < 8; ++e) accv[e] += w * bf2f_s(vv[e]);
        }
        bf16x8 sv;
        #pragma unroll
        for (int e = 0; e < 8; ++e) sv[e] = (short)f2bf(accv[e]);
        *reinterpret_cast<bf16x8*>(att + ((size_t)b * 52 + q) * 128 + a0) = sv;
    }
}

// ---------------- kernel 3: output GEMM (round-0 LDS version) ----------------
__global__ __launch_bounds__(512)
void k_out(const unsigned short* __restrict__ att,
           const unsigned short* __restrict__ Wob,
           const float* __restrict__ bo,
           float* __restrict__ out)
{
    __shared__ unsigned short As[64][72];
    __shared__ unsigned short Bs[256][72];

    const int tid  = threadIdx.x;
    const int lane = tid & 63;
    const int wave = tid >> 6;
    const int wm   = wave >> 2;
    const int wn   = wave & 3;
    const int l15  = lane & 15;
    const int lg   = lane >> 4;
    const int row0 = blockIdx.x * 64;
    const int e0   = blockIdx.y * 256;

    f32x4 acc[2][4];
    #pragma unroll
    for (int i = 0; i < 2; ++i)
        #pragma unroll
        for (int j = 0; j < 4; ++j)
            acc[i][j] = (f32x4){0.f, 0.f, 0.f, 0.f};

    for (int ko = 0; ko < 128; ko += 64) {
        {
            int r = tid >> 3;
            int c = (tid & 7) * 8;
            bf16x8 v = *reinterpret_cast<const bf16x8*>(att + (size_t)(row0 + r) * 128 + ko + c);
            *reinterpret_cast<bf16x8*>(&As[r][c]) = v;
        }
        {
            int r = tid >> 3;
            int c = (tid & 7) * 8;
            #pragma unroll
            for (int it = 0; it < 4; ++it) {
                bf16x8 v = *reinterpret_cast<const bf16x8*>(Wob + (size_t)(e0 + it * 64 + r) * 128 + ko + c);
                *reinterpret_cast<bf16x8*>(&Bs[it * 64 + r][c]) = v;
            }
        }
        __syncthreads();
        #pragma unroll
        for (int kk = 0; kk < 2; ++kk) {
            bf16x8 af[2], bfr[4];
            #pragma unroll
            for (int mi = 0; mi < 2; ++mi)
                af[mi] = *reinterpret_cast<const bf16x8*>(&As[wm * 32 + mi * 16 + l15][kk * 32 + lg * 8]);
            #pragma unroll
            for (int ni = 0; ni < 4; ++ni)
                bfr[ni] = *reinterpret_cast<const bf16x8*>(&Bs[wn * 64 + ni * 16 + l15][kk * 32 + lg * 8]);
            #pragma unroll
            for (int mi = 0; mi < 2; ++mi)
                #pragma unroll
                for (int ni = 0; ni < 4; ++ni)
                    acc[mi][ni] = __builtin_amdgcn_mfma_f32_16x16x32_bf16(af[mi], bfr[ni], acc[mi][ni], 0, 0, 0);
        }
        __syncthreads();
    }
    #pragma unroll
    for (int mi = 0; mi < 2; ++mi) {
        #pragma unroll
        for (int i = 0; i < 4; ++i) {
            int m = row0 + wm * 32 + mi * 16 + lg * 4 + i;
            #pragma unroll
            for (int ni = 0; ni < 4; ++ni) {
                int e = e0 + wn * 64 + ni * 16 + l15;
                out[(size_t)m * 1024 + e] = acc[mi][ni][i] + bo[e];
            }
        }
    }
}

extern "C" void kernel_launch(void* const* d_in, const int* in_sizes, int n_in,
                              void* d_out, int out_size, void* d_ws, size_t ws_size,
                              hipStream_t stream)
{
    const float* patches     = (const float*)d_in[0];   // [256][196][1024]
    const float* queries     = (const float*)d_in[1];   // [52][128]
    const float* Wk          = (const float*)d_in[2];   // [128][1024]
    const float* Wv          = (const float*)d_in[3];   // [128][1024]
    const float* Wo          = (const float*)d_in[4];   // [1024][128]
    const float* bo          = (const float*)d_in[5];   // [1024]
    const float* patch_pos   = (const float*)d_in[6];   // [196][128]
    const float* temperature = (const float*)d_in[7];   // [1]
    const float* prior       = (const float*)d_in[8];   // [52][196]

    float* out      = (float*)d_out;                    // [256*52][1024]
    float* attn_out = out + (size_t)256 * 52 * 1024;    // [256*52][196]

    unsigned short* Wkvb = (unsigned short*)d_ws;              // 256*1024
    unsigned short* Wob  = Wkvb + 256 * 1024;                  // 1024*128
    unsigned short* kv   = Wob + 1024 * 128;                   // 50176*256
    unsigned short* att  = kv + (size_t)50176 * 256;           // 13312*128

    k_convert <<<128, 256, 0, stream>>>(Wk, Wv, Wo, Wkvb, Wob);
    k_keysvals<<<1568, 256, 0, stream>>>(patches, Wkvb, patch_pos, kv);
    k_attn    <<<256, 1024, 0, stream>>>(kv, queries, prior, temperature, attn_out, att);
    k_out     <<<dim3(208, 4), 512, 0, stream>>>(att, Wob, bo, out);
}